// Round 16
// baseline (98.785 us; speedup 1.0000x reference)
//
#include <hip/hip_runtime.h>
#include <hip/hip_bf16.h>
#include <math.h>

#define HW 4096

typedef short bf16x8_t __attribute__((ext_vector_type(8)));   // 8 bf16 (4 VGPRs)
typedef float f32x16_t __attribute__((ext_vector_type(16)));
typedef unsigned int u32;
typedef unsigned int u32x4_t __attribute__((ext_vector_type(4)));
typedef int i32x2_t __attribute__((ext_vector_type(2)));

union castu { u32x4_t u; bf16x8_t s; };

static __device__ __forceinline__ unsigned short f2bf(float f){
    union { __bf16 b; unsigned short u; } c; c.b = (__bf16)f; return c.u;
}
static __device__ __forceinline__ u32 pk2(float lo, float hi){
    return ((u32)f2bf(hi) << 16) | (u32)f2bf(lo);
}
static __device__ __forceinline__ bf16x8_t ldb(const unsigned short* p){
    return *reinterpret_cast<const bf16x8_t*>(p);
}
static __device__ __forceinline__ bf16x8_t ld_xs(const unsigned short* p){
    uint2 lo = *(const uint2*)(p);
    uint2 hi = *(const uint2*)(p + 4);
    castu c; c.u = (u32x4_t){lo.x, lo.y, hi.x, hi.y};
    return c.s;
}
static __device__ __forceinline__ f32x16_t mfma32(bf16x8_t a, bf16x8_t b, f32x16_t c){
    return __builtin_amdgcn_mfma_f32_32x32x16_bf16(a, b, c, 0, 0, 0);
}

// Schraudolph fast exp2: bits(2^x) ~= (int)(x*2^23 + BIAS); +/-3% rel err.
// Validated on-device rounds 11-15: absmax 0.0312 <= 0.1075.
#define EXP2_MAG  8388608.0f        // 2^23
#define EXP2_BIAS 1064986816.0f     // (127<<23) - 366400

static __device__ __forceinline__ float fexp2(float x){
    return __int_as_float((int)fmaf(x, EXP2_MAG, EXP2_BIAS));
}
static __device__ __forceinline__ u32 pkexp2(float lo, float hi){
    u32 i0 = (u32)(int)fmaf(lo, EXP2_MAG, EXP2_BIAS);
    u32 i1 = (u32)(int)fmaf(hi, EXP2_MAG, EXP2_BIAS);
#if __has_builtin(__builtin_amdgcn_perm)
    return __builtin_amdgcn_perm(i1, i0, 0x07060302u);  // [i0.b2 i0.b3 i1.b2 i1.b3]
#else
    return (i1 & 0xFFFF0000u) | (i0 >> 16);
#endif
}

// C/D-layout (32x32) -> B-frag (or consumer-frag store order) via permlane32_swap.
static __device__ __forceinline__ void cd2bfrag(const u32 P[8], bf16x8_t& b0, bf16x8_t& b1){
    i32x2_t s02 = __builtin_amdgcn_permlane32_swap((int)P[0], (int)P[2], false, false);
    i32x2_t s13 = __builtin_amdgcn_permlane32_swap((int)P[1], (int)P[3], false, false);
    i32x2_t s46 = __builtin_amdgcn_permlane32_swap((int)P[4], (int)P[6], false, false);
    i32x2_t s57 = __builtin_amdgcn_permlane32_swap((int)P[5], (int)P[7], false, false);
    castu c0, c1;
    c0.u = (u32x4_t){ (u32)s02[0], (u32)s13[0], (u32)s02[1], (u32)s13[1] };
    c1.u = (u32x4_t){ (u32)s46[0], (u32)s57[0], (u32)s46[1], (u32)s57[1] };
    b0 = c0.s; b1 = c1.s;
}

#define LOG2E 1.44269504088896340736f

// Fragment-major bf16 tile layout: per 32-px tile, 1024 shorts =
// plane0[64 lanes][8] + plane1[64 lanes][8]; plane j, lane (l31,h) holds
// rows/pixel l31, channels 16j + 8h .. +7. Tile base = (b*128+tile)*1024.

// ---------------- K1: MFMA front convs + six 1x1 projections -----------------
__global__ __launch_bounds__(256, 1) void k_front_mfma(
    const float* __restrict__ x, const float* __restrict__ y,
    const float* __restrict__ conv_w, const float* __restrict__ conv_b,
    const float* __restrict__ c132_w, const float* __restrict__ c132_b,
    const float* __restrict__ q1w, const float* __restrict__ q1b,
    const float* __restrict__ k1w, const float* __restrict__ k1b,
    const float* __restrict__ q2w, const float* __restrict__ q2b,
    const float* __restrict__ k2w, const float* __restrict__ k2b,
    const float* __restrict__ q3w, const float* __restrict__ q3b,
    const float* __restrict__ k3w, const float* __restrict__ k3b,
    float* __restrict__ K1, float* __restrict__ Q2, float* __restrict__ YQ,
    unsigned short* __restrict__ Q1t, unsigned short* __restrict__ K2t,
    unsigned short* __restrict__ YKt)
{
    __shared__ unsigned short xs[4 * 68 * 36];
    __shared__ float ys[4 * 68];
    __shared__ u32 wplane[18 * 4 * 64];
    __shared__ u32 wyplane[4 * 64];
    __shared__ u32 c1plane[4 * 64];

    int tid = threadIdx.x;
    int h0 = blockIdx.x * 2, b = blockIdx.y;

    #pragma unroll
    for (int i = 0; i < 32; ++i){
        int idx = i * 256 + tid;
        int w = idx & 63, ic = (idx >> 6) & 31, dr = idx >> 11;
        int hr = h0 - 1 + dr;
        float v = (hr >= 0 && hr < 64) ? x[((b * 32 + ic) << 12) + (hr << 6) + w] : 0.f;
        xs[(dr * 68 + w + 1) * 36 + ic] = f2bf(v);
    }
    {
        int dr = tid >> 6, ic = tid & 31, side = (tid >> 5) & 1;
        xs[(dr * 68 + (side ? 65 : 0)) * 36 + ic] = 0;
    }
    for (int idx = tid; idx < 272; idx += 256){
        int dr = idx / 68, wp = idx % 68;
        int hr = h0 - 1 + dr, w = wp - 1;
        ys[idx] = (hr >= 0 && hr < 64 && w >= 0 && w < 64) ? y[(b << 12) + (hr << 6) + w] : 0.f;
    }
    for (int e = tid; e < 4608; e += 256){
        int f = e >> 8, wi = (e >> 6) & 3, ln = e & 63;
        int t = f >> 1, j = f & 1, hh = ln >> 5, ll = ln & 31;
        int ic0 = 16 * j + 8 * hh + 2 * wi;
        int co0 = 5 * (ic0 >> 2) + (ic0 & 3);
        int ic1 = ic0 + 1;
        int co1 = 5 * (ic1 >> 2) + (ic1 & 3);
        wplane[e] = pk2(conv_w[ll * 360 + co0 * 9 + t], conv_w[ll * 360 + co1 * 9 + t]);
    }
    {
        int wi = tid >> 6, ln = tid & 63, hh = ln >> 5, ll = ln & 31;
        u32 vy = 0, vc = 0;
        if (hh == 0){
            int t0 = 2 * wi, t1 = 2 * wi + 1;
            float s0 = 0.f, s1 = 0.f;
            #pragma unroll
            for (int g = 0; g < 8; ++g){
                s0 += conv_w[ll * 360 + (5 * g + 4) * 9 + t0];
                s1 += conv_w[ll * 360 + (5 * g + 4) * 9 + t1];
            }
            vy = pk2(s0, s1);
            vc = pk2(c132_w[ll * 9 + t0], c132_w[ll * 9 + t1]);
        } else if (wi == 0){
            float s0 = 0.f;
            #pragma unroll
            for (int g = 0; g < 8; ++g) s0 += conv_w[ll * 360 + (5 * g + 4) * 9 + 8];
            vy = pk2(s0, 0.f);
            vc = pk2(c132_w[ll * 9 + 8], 0.f);
        }
        wyplane[wi * 64 + ln] = vy;
        c1plane[wi * 64 + ln] = vc;
    }
    __syncthreads();

    int lane = tid & 63, wid = tid >> 6;
    int l31 = lane & 31, h = lane >> 5;
    int wr = wid >> 1, toff = (wid & 1) * 32;
    int wpB = toff + l31;

    bf16x8_t wA[18];
    #pragma unroll
    for (int f = 0; f < 18; ++f){
        castu c;
        c.u = (u32x4_t){ wplane[(f * 4 + 0) * 64 + lane], wplane[(f * 4 + 1) * 64 + lane],
                         wplane[(f * 4 + 2) * 64 + lane], wplane[(f * 4 + 3) * 64 + lane] };
        wA[f] = c.s;
    }
    castu wyf, c1f;
    wyf.u = (u32x4_t){ wyplane[lane], wyplane[64 + lane], wyplane[128 + lane], wyplane[192 + lane] };
    c1f.u = (u32x4_t){ c1plane[lane], c1plane[64 + lane], c1plane[128 + lane], c1plane[192 + lane] };

    float yv[8];
    #pragma unroll
    for (int i = 0; i < 8; ++i){
        int tt = 8 * h + i;
        yv[i] = (tt < 9) ? ys[(wr + tt / 3) * 68 + wpB + (tt % 3)] : 0.f;
    }
    castu yf;
    yf.u = (u32x4_t){ pk2(yv[0], yv[1]), pk2(yv[2], yv[3]), pk2(yv[4], yv[5]), pk2(yv[6], yv[7]) };

    f32x16_t accE, accO, accY, acc2;
    #pragma unroll
    for (int r = 0; r < 16; ++r){
        int oc = (r & 3) + 8 * (r >> 2) + 4 * h;
        accE[r] = 0.f; accO[r] = 0.f;
        accY[r] = conv_b[oc]; acc2[r] = c132_b[oc];
    }
    #pragma unroll
    for (int t = 0; t < 9; ++t){
        int base = ((wr + t / 3) * 68 + wpB + (t % 3)) * 36 + 8 * h;
        bf16x8_t b0 = ld_xs(xs + base);
        bf16x8_t b1 = ld_xs(xs + base + 16);
        if (t & 1){
            accO = mfma32(wA[t * 2 + 0], b0, accO);
            accO = mfma32(wA[t * 2 + 1], b1, accO);
        } else {
            accE = mfma32(wA[t * 2 + 0], b0, accE);
            accE = mfma32(wA[t * 2 + 1], b1, accE);
        }
    }
    accY = mfma32(wyf.s, yf.s, accY);
    acc2 = mfma32(c1f.s, yf.s, acc2);

    f32x16_t x1v;
    #pragma unroll
    for (int r = 0; r < 16; ++r){
        float v = accE[r] + accO[r] + accY[r];
        x1v[r] = v > 0.f ? v : 0.f;
    }
    u32 P[8];
    bf16x8_t x1b0, x1b1, x2b0, x2b1;
    #pragma unroll
    for (int t2 = 0; t2 < 8; ++t2) P[t2] = pk2(x1v[2 * t2], x1v[2 * t2 + 1]);
    cd2bfrag(P, x1b0, x1b1);
    #pragma unroll
    for (int t2 = 0; t2 < 8; ++t2) P[t2] = pk2(acc2[2 * t2], acc2[2 * t2 + 1]);
    cd2bfrag(P, x2b0, x2b1);

    int pxg = (h0 + wr) * 64 + toff + l31;
    int tile = ((h0 + wr) << 1) + (wid & 1);
    size_t tb = ((size_t)b * 128 + tile) * 1024;    // frag-major tile base (shorts)

    // q1 -> Q1t (frag-major, pre-scaled by log2e)
    {
        f32x16_t a;
        #pragma unroll
        for (int r = 0; r < 16; ++r) a[r] = q1b[(r & 3) + 8 * (r >> 2) + 4 * h];
        const float* p0 = q1w + l31 * 32 + 8 * h;
        castu w0, w1;
        w0.u = (u32x4_t){ pk2(p0[0],p0[1]), pk2(p0[2],p0[3]), pk2(p0[4],p0[5]), pk2(p0[6],p0[7]) };
        w1.u = (u32x4_t){ pk2(p0[16],p0[17]), pk2(p0[18],p0[19]), pk2(p0[20],p0[21]), pk2(p0[22],p0[23]) };
        a = mfma32(w0.s, x1b0, a);
        a = mfma32(w1.s, x1b1, a);
        u32 Q[8];
        #pragma unroll
        for (int t2 = 0; t2 < 8; ++t2) Q[t2] = pk2(a[2 * t2] * LOG2E, a[2 * t2 + 1] * LOG2E);
        bf16x8_t f0, f1; cd2bfrag(Q, f0, f1);
        *(bf16x8_t*)(Q1t + tb + lane * 8)       = f0;
        *(bf16x8_t*)(Q1t + tb + 512 + lane * 8) = f1;
    }
    // k1 -> K1 (f32 channel-major)
    {
        f32x16_t a;
        #pragma unroll
        for (int r = 0; r < 16; ++r) a[r] = k1b[(r & 3) + 8 * (r >> 2) + 4 * h];
        const float* p0 = k1w + l31 * 32 + 8 * h;
        castu w0, w1;
        w0.u = (u32x4_t){ pk2(p0[0],p0[1]), pk2(p0[2],p0[3]), pk2(p0[4],p0[5]), pk2(p0[6],p0[7]) };
        w1.u = (u32x4_t){ pk2(p0[16],p0[17]), pk2(p0[18],p0[19]), pk2(p0[20],p0[21]), pk2(p0[22],p0[23]) };
        a = mfma32(w0.s, x1b0, a);
        a = mfma32(w1.s, x1b1, a);
        #pragma unroll
        for (int r = 0; r < 16; ++r)
            K1[(b * 32 + (r & 3) + 8 * (r >> 2) + 4 * h) * HW + pxg] = a[r];
    }
    // q2 -> Q2 (f32 channel-major)
    {
        f32x16_t a;
        #pragma unroll
        for (int r = 0; r < 16; ++r) a[r] = q2b[(r & 3) + 8 * (r >> 2) + 4 * h];
        const float* p0 = q2w + l31 * 32 + 8 * h;
        castu w0, w1;
        w0.u = (u32x4_t){ pk2(p0[0],p0[1]), pk2(p0[2],p0[3]), pk2(p0[4],p0[5]), pk2(p0[6],p0[7]) };
        w1.u = (u32x4_t){ pk2(p0[16],p0[17]), pk2(p0[18],p0[19]), pk2(p0[20],p0[21]), pk2(p0[22],p0[23]) };
        a = mfma32(w0.s, x1b0, a);
        a = mfma32(w1.s, x1b1, a);
        #pragma unroll
        for (int r = 0; r < 16; ++r)
            Q2[(b * 32 + (r & 3) + 8 * (r >> 2) + 4 * h) * HW + pxg] = a[r];
    }
    // k2 -> K2t (frag-major)
    {
        f32x16_t a;
        #pragma unroll
        for (int r = 0; r < 16; ++r) a[r] = k2b[(r & 3) + 8 * (r >> 2) + 4 * h];
        const float* p0 = k2w + l31 * 32 + 8 * h;
        castu w0, w1;
        w0.u = (u32x4_t){ pk2(p0[0],p0[1]), pk2(p0[2],p0[3]), pk2(p0[4],p0[5]), pk2(p0[6],p0[7]) };
        w1.u = (u32x4_t){ pk2(p0[16],p0[17]), pk2(p0[18],p0[19]), pk2(p0[20],p0[21]), pk2(p0[22],p0[23]) };
        a = mfma32(w0.s, x1b0, a);
        a = mfma32(w1.s, x1b1, a);
        u32 Q[8];
        #pragma unroll
        for (int t2 = 0; t2 < 8; ++t2) Q[t2] = pk2(a[2 * t2], a[2 * t2 + 1]);
        bf16x8_t f0, f1; cd2bfrag(Q, f0, f1);
        *(bf16x8_t*)(K2t + tb + lane * 8)       = f0;
        *(bf16x8_t*)(K2t + tb + 512 + lane * 8) = f1;
    }
    // q3 (x2) -> YQ (f32 channel-major)
    {
        f32x16_t a;
        #pragma unroll
        for (int r = 0; r < 16; ++r) a[r] = q3b[(r & 3) + 8 * (r >> 2) + 4 * h];
        const float* p0 = q3w + l31 * 32 + 8 * h;
        castu w0, w1;
        w0.u = (u32x4_t){ pk2(p0[0],p0[1]), pk2(p0[2],p0[3]), pk2(p0[4],p0[5]), pk2(p0[6],p0[7]) };
        w1.u = (u32x4_t){ pk2(p0[16],p0[17]), pk2(p0[18],p0[19]), pk2(p0[20],p0[21]), pk2(p0[22],p0[23]) };
        a = mfma32(w0.s, x2b0, a);
        a = mfma32(w1.s, x2b1, a);
        #pragma unroll
        for (int r = 0; r < 16; ++r)
            YQ[(b * 32 + (r & 3) + 8 * (r >> 2) + 4 * h) * HW + pxg] = a[r];
    }
    // k3 (x2) -> YKt (frag-major)
    {
        f32x16_t a;
        #pragma unroll
        for (int r = 0; r < 16; ++r) a[r] = k3b[(r & 3) + 8 * (r >> 2) + 4 * h];
        const float* p0 = k3w + l31 * 32 + 8 * h;
        castu w0, w1;
        w0.u = (u32x4_t){ pk2(p0[0],p0[1]), pk2(p0[2],p0[3]), pk2(p0[4],p0[5]), pk2(p0[6],p0[7]) };
        w1.u = (u32x4_t){ pk2(p0[16],p0[17]), pk2(p0[18],p0[19]), pk2(p0[20],p0[21]), pk2(p0[22],p0[23]) };
        a = mfma32(w0.s, x2b0, a);
        a = mfma32(w1.s, x2b1, a);
        u32 Q[8];
        #pragma unroll
        for (int t2 = 0; t2 < 8; ++t2) Q[t2] = pk2(a[2 * t2], a[2 * t2 + 1]);
        bf16x8_t f0, f1; cd2bfrag(Q, f0, f1);
        *(bf16x8_t*)(YKt + tb + lane * 8)       = f0;
        *(bf16x8_t*)(YKt + tb + 512 + lane * 8) = f1;
    }
}

// ---------------- K3: channel attention partial sums (64-px chunks) ----------
__global__ __launch_bounds__(256) void k_chan_part(
    const float* __restrict__ K1, const float* __restrict__ Q2,
    float* __restrict__ Scp)
{
    __shared__ float k1s[64 * 33];
    __shared__ float q2s[64 * 33];
    int b = blockIdx.x & 7;
    int chunk = blockIdx.x >> 3;       // 0..63
    int n0 = chunk * 64;
    int t = threadIdx.x;
    for (int i = 0; i < 8; ++i){
        int idx = i * 256 + t;
        int c = idx >> 6, nl = idx & 63;
        k1s[nl * 33 + c] = K1[(b * 32 + c) * HW + n0 + nl];
        q2s[nl * 33 + c] = Q2[(b * 32 + c) * HW + n0 + nl];
    }
    __syncthreads();
    float acc[4] = {0.f, 0.f, 0.f, 0.f};
    int d = t & 31, c0 = t >> 5;
    for (int nl = 0; nl < 64; ++nl){
        float qv = q2s[nl * 33 + d];
        #pragma unroll
        for (int i = 0; i < 4; ++i)
            acc[i] = fmaf(k1s[nl * 33 + c0 + 8 * i], qv, acc[i]);
    }
    #pragma unroll
    for (int i = 0; i < 4; ++i)
        Scp[(b * 64 + chunk) * 1024 + (c0 + 8 * i) * 32 + d] = acc[i];
}

// ---------------- K4: channel softmax + fold conv6 W2 into M2 ----------------
__global__ __launch_bounds__(1024) void k_chan_fin(
    const float* __restrict__ Scp, const float* __restrict__ c6w,
    float* __restrict__ M2)
{
    __shared__ float pc[32 * 33];
    int b = blockIdx.x;
    int t = threadIdx.x;
    int c = t >> 5, d = t & 31;
    float s = 0.f;
    for (int k = 0; k < 64; ++k) s += Scp[(b * 64 + k) * 1024 + t];
    float mx = s;
    #pragma unroll
    for (int off = 16; off >= 1; off >>= 1) mx = fmaxf(mx, __shfl_xor(mx, off));
    float e = __expf(s - mx);
    float sum = e;
    #pragma unroll
    for (int off = 16; off >= 1; off >>= 1) sum += __shfl_xor(sum, off);
    pc[c * 33 + d] = e / sum;
    __syncthreads();
    int o = t >> 5, cc = t & 31;
    float m2 = 0.f;
    #pragma unroll
    for (int dd = 0; dd < 32; ++dd)
        m2 = fmaf(c6w[o * 64 + 32 + dd], pc[cc * 33 + dd], m2);
    M2[b * 1024 + o * 32 + cc] = m2;
}

// -------- K5: MFMA stats halves: lpart[mhalf][b][n] = sum over 64 m-tiles -----
// grid 2048: b = blk&7, ntile = (blk>>3)&127, mhalf = blk>>10
__global__ __launch_bounds__(256, 2) void k_stats_mfma(
    const unsigned short* __restrict__ Q1t, const unsigned short* __restrict__ K2t,
    float* __restrict__ lpart)
{
    __shared__ float red[4][16][64];
    int t = threadIdx.x, wid = t >> 6, lane = t & 63;
    int l31 = lane & 31, h = lane >> 5;
    int b = blockIdx.x & 7;
    int ntile = (blockIdx.x >> 3) & 127;
    int mhalf = blockIdx.x >> 10;
    int n0 = ntile * 32;
    size_t qtb = ((size_t)b * 128 + ntile) * 1024;
    bf16x8_t a0 = ldb(Q1t + qtb + lane * 8);
    bf16x8_t a1 = ldb(Q1t + qtb + 512 + lane * 8);
    float accl[16];
    #pragma unroll
    for (int r = 0; r < 16; ++r) accl[r] = 0.f;
    f32x16_t zz;
    #pragma unroll
    for (int r = 0; r < 16; ++r) zz[r] = 0.f;

    const unsigned short* kp = K2t + ((size_t)b * 128 + mhalf * 64 + (wid << 4)) * 1024 + lane * 8;
    bf16x8_t b0 = ldb(kp), b1 = ldb(kp + 512);
    f32x16_t s_cur = mfma32(a0, b0, zz);
    s_cur = mfma32(a1, b1, s_cur);
    kp += 1024;
    bf16x8_t b0n = ldb(kp), b1n = ldb(kp + 512);

    #pragma unroll 4
    for (int i = 0; i < 16; ++i){
        f32x16_t s_nxt = mfma32(a0, b0n, zz);
        s_nxt = mfma32(a1, b1n, s_nxt);
        kp += (i < 14) ? 1024 : 0;
        bf16x8_t b0nn = ldb(kp), b1nn = ldb(kp + 512);
        #pragma unroll
        for (int r = 0; r < 16; ++r) accl[r] += fexp2(s_cur[r]);
        s_cur = s_nxt; b0n = b0nn; b1n = b1nn;
    }
    #pragma unroll
    for (int r = 0; r < 16; ++r) red[wid][r][lane] = accl[r];
    __syncthreads();
    if (wid != 0) return;
    #pragma unroll
    for (int r = 0; r < 16; ++r){
        float v = red[0][r][lane] + red[1][r][lane] + red[2][r][lane] + red[3][r][lane];
        #pragma unroll
        for (int off = 16; off >= 1; off >>= 1) v += __shfl_xor(v, off);
        if (l31 == 0)
            lpart[(size_t)mhalf * 32768 + b * 4096 + n0 + (r & 3) + 8 * (r >> 2) + 4 * h] = v;
    }
}

// -------- K6: combine l halves + scale YQ -> YQ2 (frag-major) -----------------
__global__ __launch_bounds__(256) void k_scale(
    const float* __restrict__ YQ, const float* __restrict__ lpart,
    unsigned short* __restrict__ YQ2)
{
    __shared__ float ls[32];
    int t = threadIdx.x;
    int b = blockIdx.x & 7, ntile = blockIdx.x >> 3;
    int n0 = ntile * 32;
    if (t < 32){
        float l = lpart[b * 4096 + n0 + t] + lpart[32768 + b * 4096 + n0 + t];
        ls[t] = 1.0f / l;
    }
    __syncthreads();
    size_t otb = ((size_t)b * 128 + ntile) * 1024;
    #pragma unroll
    for (int p = 0; p < 4; ++p){
        int idx = (p << 8) + t;
        int c = idx >> 5, n = idx & 31;
        size_t g = (size_t)(b * 32 + c) * HW + n0 + n;
        int j = n >> 4, hh = (n >> 3) & 1;
        YQ2[otb + j * 512 + (c + (hh << 5)) * 8 + (n & 7)] = f2bf(YQ[g] * ls[n]);
    }
}

// ------- K7: MFMA value pass halves -> Opart (C-layout f32 partials) ----------
// grid 2048: b = blk&7, mtile = (blk>>3)&127, nhalf = blk>>10
__global__ __launch_bounds__(256, 2) void k_attn_mfma(
    const unsigned short* __restrict__ Q1t, const unsigned short* __restrict__ K2t,
    const unsigned short* __restrict__ YQ2, float* __restrict__ Opart)
{
    __shared__ float red[4][16][64];
    int t = threadIdx.x, wid = t >> 6, lane = t & 63;
    int b = blockIdx.x & 7;
    int mtile = (blockIdx.x >> 3) & 127;
    int nhalf = blockIdx.x >> 10;
    size_t ktb = ((size_t)b * 128 + mtile) * 1024;

    bf16x8_t kb0 = ldb(K2t + ktb + lane * 8);
    bf16x8_t kb1 = ldb(K2t + ktb + 512 + lane * 8);

    f32x16_t oacc, zz;
    #pragma unroll
    for (int r = 0; r < 16; ++r){ oacc[r] = 0.f; zz[r] = 0.f; }

    size_t nbase = (size_t)b * 128 + nhalf * 64 + (wid << 4);
    const unsigned short* qp = Q1t + nbase * 1024 + lane * 8;
    const unsigned short* yp = YQ2 + nbase * 1024 + lane * 8;

    bf16x8_t a0 = ldb(qp), a1 = ldb(qp + 512);
    bf16x8_t y0 = ldb(yp), y1 = ldb(yp + 512);
    f32x16_t s_cur = mfma32(a0, kb0, zz);
    s_cur = mfma32(a1, kb1, s_cur);
    qp += 1024; yp += 1024;
    bf16x8_t a0n = ldb(qp), a1n = ldb(qp + 512);
    bf16x8_t y0n = ldb(yp), y1n = ldb(yp + 512);

    #pragma unroll 4
    for (int i = 0; i < 16; ++i){
        f32x16_t s_nxt = mfma32(a0n, kb0, zz);
        s_nxt = mfma32(a1n, kb1, s_nxt);
        int adv = (i < 14) ? 1024 : 0;
        qp += adv; yp += adv;
        bf16x8_t a0nn = ldb(qp), a1nn = ldb(qp + 512);
        bf16x8_t y0nn = ldb(yp), y1nn = ldb(yp + 512);
        u32 P[8];
        #pragma unroll
        for (int tt = 0; tt < 8; ++tt)
            P[tt] = pkexp2(s_cur[2 * tt], s_cur[2 * tt + 1]);
        bf16x8_t e0, e1;
        cd2bfrag(P, e0, e1);
        __builtin_amdgcn_s_setprio(1);
        oacc = mfma32(y0, e0, oacc);
        oacc = mfma32(y1, e1, oacc);
        __builtin_amdgcn_s_setprio(0);
        s_cur = s_nxt;
        a0n = a0nn; a1n = a1nn;
        y0 = y0n; y1 = y1n; y0n = y0nn; y1n = y1nn;
    }
    #pragma unroll
    for (int r = 0; r < 16; ++r) red[wid][r][lane] = oacc[r];
    __syncthreads();
    if (wid != 0) return;
    float* op = Opart + (((size_t)nhalf * 8 + b) * 128 + mtile) * 1024;
    #pragma unroll
    for (int r = 0; r < 16; ++r)
        op[r * 64 + lane] = red[0][r][lane] + red[1][r][lane] + red[2][r][lane] + red[3][r][lane];
}

// ------- K8: epilogue: sum halves + conv6 + M2*YK + residual ------------------
// grid 256: b = blk&7, mgrp = blk>>3; wave wid -> mtile = mgrp*4 + wid
__global__ __launch_bounds__(256) void k_epi(
    const float* __restrict__ Opart, const unsigned short* __restrict__ YKt,
    const float* __restrict__ M2, const float* __restrict__ c6w, const float* __restrict__ c6b,
    const float* __restrict__ x, float* __restrict__ xout)
{
    int t = threadIdx.x, wid = t >> 6, lane = t & 63;
    int l31 = lane & 31, h = lane >> 5;
    int b = blockIdx.x & 7;
    int mtile = (blockIdx.x >> 3) * 4 + wid;
    int m0 = mtile * 32;
    size_t ktb = ((size_t)b * 128 + mtile) * 1024;

    const float* p0h = Opart + ((size_t)b * 128 + mtile) * 1024;
    const float* p1h = Opart + (((size_t)8 + b) * 128 + mtile) * 1024;
    f32x16_t oacc;
    #pragma unroll
    for (int r = 0; r < 16; ++r)
        oacc[r] = p0h[r * 64 + lane] + p1h[r * 64 + lane];

    u32 P[8];
    #pragma unroll
    for (int tt = 0; tt < 8; ++tt) P[tt] = pk2(oacc[2 * tt], oacc[2 * tt + 1]);
    bf16x8_t xb0, xb1;
    cd2bfrag(P, xb0, xb1);

    const float* w1p = c6w + l31 * 64;
    const float* m2p = M2 + b * 1024 + l31 * 32;
    int cb0 = 8 * h, cb1 = 16 + 8 * h;
    castu wa0, wa1, ma0, ma1;
    wa0.u = (u32x4_t){ pk2(w1p[cb0], w1p[cb0+1]), pk2(w1p[cb0+2], w1p[cb0+3]),
                       pk2(w1p[cb0+4], w1p[cb0+5]), pk2(w1p[cb0+6], w1p[cb0+7]) };
    wa1.u = (u32x4_t){ pk2(w1p[cb1], w1p[cb1+1]), pk2(w1p[cb1+2], w1p[cb1+3]),
                       pk2(w1p[cb1+4], w1p[cb1+5]), pk2(w1p[cb1+6], w1p[cb1+7]) };
    ma0.u = (u32x4_t){ pk2(m2p[cb0], m2p[cb0+1]), pk2(m2p[cb0+2], m2p[cb0+3]),
                       pk2(m2p[cb0+4], m2p[cb0+5]), pk2(m2p[cb0+6], m2p[cb0+7]) };
    ma1.u = (u32x4_t){ pk2(m2p[cb1], m2p[cb1+1]), pk2(m2p[cb1+2], m2p[cb1+3]),
                       pk2(m2p[cb1+4], m2p[cb1+5]), pk2(m2p[cb1+6], m2p[cb1+7]) };
    bf16x8_t ykb0 = ldb(YKt + ktb + lane * 8);
    bf16x8_t ykb1 = ldb(YKt + ktb + 512 + lane * 8);

    f32x16_t facc;
    #pragma unroll
    for (int r = 0; r < 16; ++r) facc[r] = c6b[(r & 3) + 8 * (r >> 2) + 4 * h];
    facc = mfma32(wa0.s, xb0, facc);
    facc = mfma32(wa1.s, xb1, facc);
    facc = mfma32(ma0.s, ykb0, facc);
    facc = mfma32(ma1.s, ykb1, facc);

    #pragma unroll
    for (int r = 0; r < 16; ++r){
        int o = (r & 3) + 8 * (r >> 2) + 4 * h;
        size_t gi = ((size_t)(b * 32 + o) << 12) + m0 + l31;
        xout[gi] = x[gi] + facc[r];
    }
}

// ---------------- K9: score conv + residual on y (LDS-staged) -----------------
__global__ __launch_bounds__(256) void k_score(
    const float* __restrict__ xout, const float* __restrict__ y,
    const float* __restrict__ sw, const float* __restrict__ sb,
    float* __restrict__ yout)
{
    __shared__ float xs[3][32][66];
    __shared__ float red[4][64];
    int tid = threadIdx.x;
    int b = blockIdx.x & 7, h = blockIdx.x >> 3;
    for (int i = 0; i < 24; ++i){
        int idx = i * 256 + tid;
        int w = idx & 63, ic = (idx >> 6) & 31, dr = idx >> 11;
        int hr = h + dr - 1;
        xs[dr][ic][1 + w] = (hr >= 0 && hr < 64) ? xout[((b * 32 + ic) << 12) + (hr << 6) + w] : 0.f;
    }
    if (tid < 96){ xs[tid >> 5][tid & 31][0] = 0.f; }
    else if (tid < 192){ int u = tid - 96; xs[u >> 5][u & 31][65] = 0.f; }
    __syncthreads();
    int w = tid & 63, icg = tid >> 6;
    float p = 0.f;
    #pragma unroll
    for (int i = 0; i < 8; ++i){
        int ic = icg * 8 + i;
        #pragma unroll
        for (int tap = 0; tap < 9; ++tap)
            p = fmaf(sw[ic * 9 + tap], xs[tap / 3][ic][w + tap % 3], p);
    }
    red[icg][w] = p;
    __syncthreads();
    if (tid < 64){
        int px = (h << 6) + tid;
        yout[b * HW + px] = y[b * HW + px] + sb[0]
                          + red[0][tid] + red[1][tid] + red[2][tid] + red[3][tid];
    }
}

extern "C" void kernel_launch(void* const* d_in, const int* in_sizes, int n_in,
                              void* d_out, int out_size, void* d_ws, size_t ws_size,
                              hipStream_t stream)
{
    (void)in_sizes; (void)n_in; (void)out_size; (void)ws_size;
    const float* x      = (const float*)d_in[0];
    const float* y      = (const float*)d_in[1];
    const float* conv_w = (const float*)d_in[2];
    const float* conv_b = (const float*)d_in[3];
    const float* score_w= (const float*)d_in[4];
    const float* score_b= (const float*)d_in[5];
    const float* c132_w = (const float*)d_in[6];
    const float* c132_b = (const float*)d_in[7];
    const float* q1w = (const float*)d_in[8];  const float* q1b = (const float*)d_in[9];
    const float* k1w = (const float*)d_in[10]; const float* k1b = (const float*)d_in[11];
    const float* q2w = (const float*)d_in[12]; const float* q2b = (const float*)d_in[13];
    const float* k2w = (const float*)d_in[14]; const float* k2b = (const float*)d_in[15];
    const float* q3w = (const float*)d_in[16]; const float* q3b = (const float*)d_in[17];
    const float* k3w = (const float*)d_in[18]; const float* k3b = (const float*)d_in[19];
    const float* c6w = (const float*)d_in[20]; const float* c6b = (const float*)d_in[21];

    float* ws = (float*)d_ws;
    const size_t SZ = 1048576;            // 8*32*4096
    float* Scp = ws;                      // 524288 f32
    float* M2  = ws + 524288;             // 8192 f32
    float* K1  = ws + 2 * SZ;             // 1M f32
    float* Q2  = ws + 3 * SZ;             // 1M f32
    float* YQf = ws + 4 * SZ;             // 1M f32
    unsigned short* Q1t = (unsigned short*)(ws + 5 * SZ);            // 1M bf16 (frag-major)
    unsigned short* K2t = (unsigned short*)(ws + 5 * SZ + SZ / 2);   // 1M bf16 (frag-major)
    unsigned short* YKt = (unsigned short*)(ws + 6 * SZ);            // 1M bf16 (frag-major)
    unsigned short* YQ2 = (unsigned short*)(ws + 6 * SZ + SZ / 2);   // 1M bf16 (frag-major)
    float* lpart = ws + 7 * SZ;           // 65536 f32 (2 halves x 8b x 4096)
    float* Opart = ws + 8 * SZ;           // 2M f32 (2 halves x 8b x 128 x 1024)

    float* xout = (float*)d_out;
    float* yout = xout + SZ;

    k_front_mfma<<<dim3(32, 8), 256, 0, stream>>>(
        x, y, conv_w, conv_b, c132_w, c132_b,
        q1w, q1b, k1w, k1b, q2w, q2b, k2w, k2b, q3w, q3b, k3w, k3b,
        K1, Q2, YQf, Q1t, K2t, YKt);
    k_chan_part<<<512, 256, 0, stream>>>(K1, Q2, Scp);
    k_chan_fin<<<8, 1024, 0, stream>>>(Scp, c6w, M2);
    k_stats_mfma<<<2048, 256, 0, stream>>>(Q1t, K2t, lpart);
    k_scale<<<1024, 256, 0, stream>>>(YQf, lpart, YQ2);
    k_attn_mfma<<<2048, 256, 0, stream>>>(Q1t, K2t, YQ2, Opart);
    k_epi<<<256, 256, 0, stream>>>(Opart, YKt, M2, c6w, c6b, x, xout);
    k_score<<<512, 256, 0, stream>>>(xout, y, score_w, score_b, yout);
}

// Round 17
// 91.920 us; speedup vs baseline: 1.0747x; 1.0747x over previous
//
#include <hip/hip_runtime.h>
#include <hip/hip_bf16.h>
#include <math.h>

#define HW 4096

typedef short bf16x8_t __attribute__((ext_vector_type(8)));   // 8 bf16 (4 VGPRs)
typedef float f32x16_t __attribute__((ext_vector_type(16)));
typedef unsigned int u32;
typedef unsigned int u32x4_t __attribute__((ext_vector_type(4)));
typedef int i32x2_t __attribute__((ext_vector_type(2)));

union castu { u32x4_t u; bf16x8_t s; };

static __device__ __forceinline__ unsigned short f2bf(float f){
    union { __bf16 b; unsigned short u; } c; c.b = (__bf16)f; return c.u;
}
static __device__ __forceinline__ u32 pk2(float lo, float hi){
    return ((u32)f2bf(hi) << 16) | (u32)f2bf(lo);
}
static __device__ __forceinline__ bf16x8_t ldb(const unsigned short* p){
    return *reinterpret_cast<const bf16x8_t*>(p);
}
static __device__ __forceinline__ bf16x8_t ld_xs(const unsigned short* p){
    uint2 lo = *(const uint2*)(p);
    uint2 hi = *(const uint2*)(p + 4);
    castu c; c.u = (u32x4_t){lo.x, lo.y, hi.x, hi.y};
    return c.s;
}
static __device__ __forceinline__ f32x16_t mfma32(bf16x8_t a, bf16x8_t b, f32x16_t c){
    return __builtin_amdgcn_mfma_f32_32x32x16_bf16(a, b, c, 0, 0, 0);
}

// Schraudolph fast exp2: bits(2^x) ~= (int)(x*2^23 + BIAS); +/-3% rel err.
// Validated on-device rounds 11-16: absmax 0.0312 <= 0.1075.
#define EXP2_MAG  8388608.0f        // 2^23
#define EXP2_BIAS 1064986816.0f     // (127<<23) - 366400

static __device__ __forceinline__ float fexp2(float x){
    return __int_as_float((int)fmaf(x, EXP2_MAG, EXP2_BIAS));
}
static __device__ __forceinline__ u32 pkexp2(float lo, float hi){
    u32 i0 = (u32)(int)fmaf(lo, EXP2_MAG, EXP2_BIAS);
    u32 i1 = (u32)(int)fmaf(hi, EXP2_MAG, EXP2_BIAS);
#if __has_builtin(__builtin_amdgcn_perm)
    return __builtin_amdgcn_perm(i1, i0, 0x07060302u);  // [i0.b2 i0.b3 i1.b2 i1.b3]
#else
    return (i1 & 0xFFFF0000u) | (i0 >> 16);
#endif
}

// C/D-layout (32x32) -> B-frag (or consumer-frag store order) via permlane32_swap.
static __device__ __forceinline__ void cd2bfrag(const u32 P[8], bf16x8_t& b0, bf16x8_t& b1){
    i32x2_t s02 = __builtin_amdgcn_permlane32_swap((int)P[0], (int)P[2], false, false);
    i32x2_t s13 = __builtin_amdgcn_permlane32_swap((int)P[1], (int)P[3], false, false);
    i32x2_t s46 = __builtin_amdgcn_permlane32_swap((int)P[4], (int)P[6], false, false);
    i32x2_t s57 = __builtin_amdgcn_permlane32_swap((int)P[5], (int)P[7], false, false);
    castu c0, c1;
    c0.u = (u32x4_t){ (u32)s02[0], (u32)s13[0], (u32)s02[1], (u32)s13[1] };
    c1.u = (u32x4_t){ (u32)s46[0], (u32)s57[0], (u32)s46[1], (u32)s57[1] };
    b0 = c0.s; b1 = c1.s;
}

#define LOG2E 1.44269504088896340736f

// Fragment-major bf16 tile layout: per 32-px tile, 1024 shorts =
// plane0[64 lanes][8] + plane1[64 lanes][8]; plane j, lane (l31,h) holds
// rows/pixel l31, channels 16j + 8h .. +7. Tile base = (b*128+tile)*1024.

// ---------------- K1: MFMA front convs + six 1x1 projections -----------------
__global__ __launch_bounds__(256, 1) void k_front_mfma(
    const float* __restrict__ x, const float* __restrict__ y,
    const float* __restrict__ conv_w, const float* __restrict__ conv_b,
    const float* __restrict__ c132_w, const float* __restrict__ c132_b,
    const float* __restrict__ q1w, const float* __restrict__ q1b,
    const float* __restrict__ k1w, const float* __restrict__ k1b,
    const float* __restrict__ q2w, const float* __restrict__ q2b,
    const float* __restrict__ k2w, const float* __restrict__ k2b,
    const float* __restrict__ q3w, const float* __restrict__ q3b,
    const float* __restrict__ k3w, const float* __restrict__ k3b,
    float* __restrict__ K1, float* __restrict__ Q2, float* __restrict__ YQ,
    unsigned short* __restrict__ Q1t, unsigned short* __restrict__ K2t,
    unsigned short* __restrict__ YKt)
{
    __shared__ unsigned short xs[4 * 68 * 36];
    __shared__ float ys[4 * 68];
    __shared__ u32 wplane[18 * 4 * 64];
    __shared__ u32 wyplane[4 * 64];
    __shared__ u32 c1plane[4 * 64];

    int tid = threadIdx.x;
    int h0 = blockIdx.x * 2, b = blockIdx.y;

    #pragma unroll
    for (int i = 0; i < 32; ++i){
        int idx = i * 256 + tid;
        int w = idx & 63, ic = (idx >> 6) & 31, dr = idx >> 11;
        int hr = h0 - 1 + dr;
        float v = (hr >= 0 && hr < 64) ? x[((b * 32 + ic) << 12) + (hr << 6) + w] : 0.f;
        xs[(dr * 68 + w + 1) * 36 + ic] = f2bf(v);
    }
    {
        int dr = tid >> 6, ic = tid & 31, side = (tid >> 5) & 1;
        xs[(dr * 68 + (side ? 65 : 0)) * 36 + ic] = 0;
    }
    for (int idx = tid; idx < 272; idx += 256){
        int dr = idx / 68, wp = idx % 68;
        int hr = h0 - 1 + dr, w = wp - 1;
        ys[idx] = (hr >= 0 && hr < 64 && w >= 0 && w < 64) ? y[(b << 12) + (hr << 6) + w] : 0.f;
    }
    for (int e = tid; e < 4608; e += 256){
        int f = e >> 8, wi = (e >> 6) & 3, ln = e & 63;
        int t = f >> 1, j = f & 1, hh = ln >> 5, ll = ln & 31;
        int ic0 = 16 * j + 8 * hh + 2 * wi;
        int co0 = 5 * (ic0 >> 2) + (ic0 & 3);
        int ic1 = ic0 + 1;
        int co1 = 5 * (ic1 >> 2) + (ic1 & 3);
        wplane[e] = pk2(conv_w[ll * 360 + co0 * 9 + t], conv_w[ll * 360 + co1 * 9 + t]);
    }
    {
        int wi = tid >> 6, ln = tid & 63, hh = ln >> 5, ll = ln & 31;
        u32 vy = 0, vc = 0;
        if (hh == 0){
            int t0 = 2 * wi, t1 = 2 * wi + 1;
            float s0 = 0.f, s1 = 0.f;
            #pragma unroll
            for (int g = 0; g < 8; ++g){
                s0 += conv_w[ll * 360 + (5 * g + 4) * 9 + t0];
                s1 += conv_w[ll * 360 + (5 * g + 4) * 9 + t1];
            }
            vy = pk2(s0, s1);
            vc = pk2(c132_w[ll * 9 + t0], c132_w[ll * 9 + t1]);
        } else if (wi == 0){
            float s0 = 0.f;
            #pragma unroll
            for (int g = 0; g < 8; ++g) s0 += conv_w[ll * 360 + (5 * g + 4) * 9 + 8];
            vy = pk2(s0, 0.f);
            vc = pk2(c132_w[ll * 9 + 8], 0.f);
        }
        wyplane[wi * 64 + ln] = vy;
        c1plane[wi * 64 + ln] = vc;
    }
    __syncthreads();

    int lane = tid & 63, wid = tid >> 6;
    int l31 = lane & 31, h = lane >> 5;
    int wr = wid >> 1, toff = (wid & 1) * 32;
    int wpB = toff + l31;

    bf16x8_t wA[18];
    #pragma unroll
    for (int f = 0; f < 18; ++f){
        castu c;
        c.u = (u32x4_t){ wplane[(f * 4 + 0) * 64 + lane], wplane[(f * 4 + 1) * 64 + lane],
                         wplane[(f * 4 + 2) * 64 + lane], wplane[(f * 4 + 3) * 64 + lane] };
        wA[f] = c.s;
    }
    castu wyf, c1f;
    wyf.u = (u32x4_t){ wyplane[lane], wyplane[64 + lane], wyplane[128 + lane], wyplane[192 + lane] };
    c1f.u = (u32x4_t){ c1plane[lane], c1plane[64 + lane], c1plane[128 + lane], c1plane[192 + lane] };

    float yv[8];
    #pragma unroll
    for (int i = 0; i < 8; ++i){
        int tt = 8 * h + i;
        yv[i] = (tt < 9) ? ys[(wr + tt / 3) * 68 + wpB + (tt % 3)] : 0.f;
    }
    castu yf;
    yf.u = (u32x4_t){ pk2(yv[0], yv[1]), pk2(yv[2], yv[3]), pk2(yv[4], yv[5]), pk2(yv[6], yv[7]) };

    f32x16_t accE, accO, accY, acc2;
    #pragma unroll
    for (int r = 0; r < 16; ++r){
        int oc = (r & 3) + 8 * (r >> 2) + 4 * h;
        accE[r] = 0.f; accO[r] = 0.f;
        accY[r] = conv_b[oc]; acc2[r] = c132_b[oc];
    }
    #pragma unroll
    for (int t = 0; t < 9; ++t){
        int base = ((wr + t / 3) * 68 + wpB + (t % 3)) * 36 + 8 * h;
        bf16x8_t b0 = ld_xs(xs + base);
        bf16x8_t b1 = ld_xs(xs + base + 16);
        if (t & 1){
            accO = mfma32(wA[t * 2 + 0], b0, accO);
            accO = mfma32(wA[t * 2 + 1], b1, accO);
        } else {
            accE = mfma32(wA[t * 2 + 0], b0, accE);
            accE = mfma32(wA[t * 2 + 1], b1, accE);
        }
    }
    accY = mfma32(wyf.s, yf.s, accY);
    acc2 = mfma32(c1f.s, yf.s, acc2);

    f32x16_t x1v;
    #pragma unroll
    for (int r = 0; r < 16; ++r){
        float v = accE[r] + accO[r] + accY[r];
        x1v[r] = v > 0.f ? v : 0.f;
    }
    u32 P[8];
    bf16x8_t x1b0, x1b1, x2b0, x2b1;
    #pragma unroll
    for (int t2 = 0; t2 < 8; ++t2) P[t2] = pk2(x1v[2 * t2], x1v[2 * t2 + 1]);
    cd2bfrag(P, x1b0, x1b1);
    #pragma unroll
    for (int t2 = 0; t2 < 8; ++t2) P[t2] = pk2(acc2[2 * t2], acc2[2 * t2 + 1]);
    cd2bfrag(P, x2b0, x2b1);

    int pxg = (h0 + wr) * 64 + toff + l31;
    int tile = ((h0 + wr) << 1) + (wid & 1);
    size_t tb = ((size_t)b * 128 + tile) * 1024;    // frag-major tile base (shorts)

    // q1 -> Q1t (frag-major, pre-scaled by log2e)
    {
        f32x16_t a;
        #pragma unroll
        for (int r = 0; r < 16; ++r) a[r] = q1b[(r & 3) + 8 * (r >> 2) + 4 * h];
        const float* p0 = q1w + l31 * 32 + 8 * h;
        castu w0, w1;
        w0.u = (u32x4_t){ pk2(p0[0],p0[1]), pk2(p0[2],p0[3]), pk2(p0[4],p0[5]), pk2(p0[6],p0[7]) };
        w1.u = (u32x4_t){ pk2(p0[16],p0[17]), pk2(p0[18],p0[19]), pk2(p0[20],p0[21]), pk2(p0[22],p0[23]) };
        a = mfma32(w0.s, x1b0, a);
        a = mfma32(w1.s, x1b1, a);
        u32 Q[8];
        #pragma unroll
        for (int t2 = 0; t2 < 8; ++t2) Q[t2] = pk2(a[2 * t2] * LOG2E, a[2 * t2 + 1] * LOG2E);
        bf16x8_t f0, f1; cd2bfrag(Q, f0, f1);
        *(bf16x8_t*)(Q1t + tb + lane * 8)       = f0;
        *(bf16x8_t*)(Q1t + tb + 512 + lane * 8) = f1;
    }
    // k1 -> K1 (f32 channel-major)
    {
        f32x16_t a;
        #pragma unroll
        for (int r = 0; r < 16; ++r) a[r] = k1b[(r & 3) + 8 * (r >> 2) + 4 * h];
        const float* p0 = k1w + l31 * 32 + 8 * h;
        castu w0, w1;
        w0.u = (u32x4_t){ pk2(p0[0],p0[1]), pk2(p0[2],p0[3]), pk2(p0[4],p0[5]), pk2(p0[6],p0[7]) };
        w1.u = (u32x4_t){ pk2(p0[16],p0[17]), pk2(p0[18],p0[19]), pk2(p0[20],p0[21]), pk2(p0[22],p0[23]) };
        a = mfma32(w0.s, x1b0, a);
        a = mfma32(w1.s, x1b1, a);
        #pragma unroll
        for (int r = 0; r < 16; ++r)
            K1[(b * 32 + (r & 3) + 8 * (r >> 2) + 4 * h) * HW + pxg] = a[r];
    }
    // q2 -> Q2 (f32 channel-major)
    {
        f32x16_t a;
        #pragma unroll
        for (int r = 0; r < 16; ++r) a[r] = q2b[(r & 3) + 8 * (r >> 2) + 4 * h];
        const float* p0 = q2w + l31 * 32 + 8 * h;
        castu w0, w1;
        w0.u = (u32x4_t){ pk2(p0[0],p0[1]), pk2(p0[2],p0[3]), pk2(p0[4],p0[5]), pk2(p0[6],p0[7]) };
        w1.u = (u32x4_t){ pk2(p0[16],p0[17]), pk2(p0[18],p0[19]), pk2(p0[20],p0[21]), pk2(p0[22],p0[23]) };
        a = mfma32(w0.s, x1b0, a);
        a = mfma32(w1.s, x1b1, a);
        #pragma unroll
        for (int r = 0; r < 16; ++r)
            Q2[(b * 32 + (r & 3) + 8 * (r >> 2) + 4 * h) * HW + pxg] = a[r];
    }
    // k2 -> K2t (frag-major)
    {
        f32x16_t a;
        #pragma unroll
        for (int r = 0; r < 16; ++r) a[r] = k2b[(r & 3) + 8 * (r >> 2) + 4 * h];
        const float* p0 = k2w + l31 * 32 + 8 * h;
        castu w0, w1;
        w0.u = (u32x4_t){ pk2(p0[0],p0[1]), pk2(p0[2],p0[3]), pk2(p0[4],p0[5]), pk2(p0[6],p0[7]) };
        w1.u = (u32x4_t){ pk2(p0[16],p0[17]), pk2(p0[18],p0[19]), pk2(p0[20],p0[21]), pk2(p0[22],p0[23]) };
        a = mfma32(w0.s, x1b0, a);
        a = mfma32(w1.s, x1b1, a);
        u32 Q[8];
        #pragma unroll
        for (int t2 = 0; t2 < 8; ++t2) Q[t2] = pk2(a[2 * t2], a[2 * t2 + 1]);
        bf16x8_t f0, f1; cd2bfrag(Q, f0, f1);
        *(bf16x8_t*)(K2t + tb + lane * 8)       = f0;
        *(bf16x8_t*)(K2t + tb + 512 + lane * 8) = f1;
    }
    // q3 (x2) -> YQ (f32 channel-major)
    {
        f32x16_t a;
        #pragma unroll
        for (int r = 0; r < 16; ++r) a[r] = q3b[(r & 3) + 8 * (r >> 2) + 4 * h];
        const float* p0 = q3w + l31 * 32 + 8 * h;
        castu w0, w1;
        w0.u = (u32x4_t){ pk2(p0[0],p0[1]), pk2(p0[2],p0[3]), pk2(p0[4],p0[5]), pk2(p0[6],p0[7]) };
        w1.u = (u32x4_t){ pk2(p0[16],p0[17]), pk2(p0[18],p0[19]), pk2(p0[20],p0[21]), pk2(p0[22],p0[23]) };
        a = mfma32(w0.s, x2b0, a);
        a = mfma32(w1.s, x2b1, a);
        #pragma unroll
        for (int r = 0; r < 16; ++r)
            YQ[(b * 32 + (r & 3) + 8 * (r >> 2) + 4 * h) * HW + pxg] = a[r];
    }
    // k3 (x2) -> YKt (frag-major)
    {
        f32x16_t a;
        #pragma unroll
        for (int r = 0; r < 16; ++r) a[r] = k3b[(r & 3) + 8 * (r >> 2) + 4 * h];
        const float* p0 = k3w + l31 * 32 + 8 * h;
        castu w0, w1;
        w0.u = (u32x4_t){ pk2(p0[0],p0[1]), pk2(p0[2],p0[3]), pk2(p0[4],p0[5]), pk2(p0[6],p0[7]) };
        w1.u = (u32x4_t){ pk2(p0[16],p0[17]), pk2(p0[18],p0[19]), pk2(p0[20],p0[21]), pk2(p0[22],p0[23]) };
        a = mfma32(w0.s, x2b0, a);
        a = mfma32(w1.s, x2b1, a);
        u32 Q[8];
        #pragma unroll
        for (int t2 = 0; t2 < 8; ++t2) Q[t2] = pk2(a[2 * t2], a[2 * t2 + 1]);
        bf16x8_t f0, f1; cd2bfrag(Q, f0, f1);
        *(bf16x8_t*)(YKt + tb + lane * 8)       = f0;
        *(bf16x8_t*)(YKt + tb + 512 + lane * 8) = f1;
    }
}

// ---------------- K3: channel attention partial sums (64-px chunks) ----------
__global__ __launch_bounds__(256) void k_chan_part(
    const float* __restrict__ K1, const float* __restrict__ Q2,
    float* __restrict__ Scp)
{
    __shared__ float k1s[64 * 33];
    __shared__ float q2s[64 * 33];
    int b = blockIdx.x & 7;
    int chunk = blockIdx.x >> 3;       // 0..63
    int n0 = chunk * 64;
    int t = threadIdx.x;
    for (int i = 0; i < 8; ++i){
        int idx = i * 256 + t;
        int c = idx >> 6, nl = idx & 63;
        k1s[nl * 33 + c] = K1[(b * 32 + c) * HW + n0 + nl];
        q2s[nl * 33 + c] = Q2[(b * 32 + c) * HW + n0 + nl];
    }
    __syncthreads();
    float acc[4] = {0.f, 0.f, 0.f, 0.f};
    int d = t & 31, c0 = t >> 5;
    for (int nl = 0; nl < 64; ++nl){
        float qv = q2s[nl * 33 + d];
        #pragma unroll
        for (int i = 0; i < 4; ++i)
            acc[i] = fmaf(k1s[nl * 33 + c0 + 8 * i], qv, acc[i]);
    }
    #pragma unroll
    for (int i = 0; i < 4; ++i)
        Scp[(b * 64 + chunk) * 1024 + (c0 + 8 * i) * 32 + d] = acc[i];
}

// ---------------- K4: channel softmax + fold conv6 W2 into M2 ----------------
__global__ __launch_bounds__(1024) void k_chan_fin(
    const float* __restrict__ Scp, const float* __restrict__ c6w,
    float* __restrict__ M2)
{
    __shared__ float pc[32 * 33];
    int b = blockIdx.x;
    int t = threadIdx.x;
    int c = t >> 5, d = t & 31;
    float s = 0.f;
    for (int k = 0; k < 64; ++k) s += Scp[(b * 64 + k) * 1024 + t];
    float mx = s;
    #pragma unroll
    for (int off = 16; off >= 1; off >>= 1) mx = fmaxf(mx, __shfl_xor(mx, off));
    float e = __expf(s - mx);
    float sum = e;
    #pragma unroll
    for (int off = 16; off >= 1; off >>= 1) sum += __shfl_xor(sum, off);
    pc[c * 33 + d] = e / sum;
    __syncthreads();
    int o = t >> 5, cc = t & 31;
    float m2 = 0.f;
    #pragma unroll
    for (int dd = 0; dd < 32; ++dd)
        m2 = fmaf(c6w[o * 64 + 32 + dd], pc[cc * 33 + dd], m2);
    M2[b * 1024 + o * 32 + cc] = m2;
}

// -------- K5: MFMA stats, 2 n-tiles/block (shared K stream); YQ scale -> YQ2 --
// grid 512: b = blk&7, npair = blk>>3 (n-tiles 2p, 2p+1)
__global__ __launch_bounds__(256, 2) void k_stats_mfma(
    const unsigned short* __restrict__ Q1t, const unsigned short* __restrict__ K2t,
    const float* __restrict__ YQ, unsigned short* __restrict__ YQ2)
{
    __shared__ float redA[4][16][64];
    __shared__ float redB[4][16][64];
    __shared__ float ls[64];
    int t = threadIdx.x, wid = t >> 6, lane = t & 63;
    int l31 = lane & 31, h = lane >> 5;
    int b = blockIdx.x & 7, npair = blockIdx.x >> 3;
    int nA = npair * 2;
    size_t qtbA = ((size_t)b * 128 + nA) * 1024;
    bf16x8_t aA0 = ldb(Q1t + qtbA + lane * 8);
    bf16x8_t aA1 = ldb(Q1t + qtbA + 512 + lane * 8);
    bf16x8_t aB0 = ldb(Q1t + qtbA + 1024 + lane * 8);
    bf16x8_t aB1 = ldb(Q1t + qtbA + 1536 + lane * 8);
    float acclA[16], acclB[16];
    #pragma unroll
    for (int r = 0; r < 16; ++r){ acclA[r] = 0.f; acclB[r] = 0.f; }
    f32x16_t zz;
    #pragma unroll
    for (int r = 0; r < 16; ++r) zz[r] = 0.f;

    const unsigned short* kp = K2t + ((size_t)b * 128 + (wid << 5)) * 1024 + lane * 8;
    bf16x8_t b0 = ldb(kp), b1 = ldb(kp + 512);
    kp += 1024;
    bf16x8_t b0n = ldb(kp), b1n = ldb(kp + 512);

    #pragma unroll 2
    for (int i = 0; i < 32; ++i){
        f32x16_t sA = mfma32(aA0, b0, zz);
        sA = mfma32(aA1, b1, sA);
        f32x16_t sB = mfma32(aB0, b0, zz);
        sB = mfma32(aB1, b1, sB);
        kp += (i < 30) ? 1024 : 0;
        bf16x8_t b0nn = ldb(kp), b1nn = ldb(kp + 512);
        #pragma unroll
        for (int r = 0; r < 16; ++r) acclA[r] += fexp2(sA[r]);
        #pragma unroll
        for (int r = 0; r < 16; ++r) acclB[r] += fexp2(sB[r]);
        b0 = b0n; b1 = b1n; b0n = b0nn; b1n = b1nn;
    }
    #pragma unroll
    for (int r = 0; r < 16; ++r){
        redA[wid][r][lane] = acclA[r];
        redB[wid][r][lane] = acclB[r];
    }
    __syncthreads();
    if (wid < 2){
        const float* rp = (wid == 0) ? &redA[0][0][0] : &redB[0][0][0];
        #pragma unroll
        for (int r = 0; r < 16; ++r){
            float v = rp[r * 64 + lane] + rp[1024 + r * 64 + lane]
                    + rp[2048 + r * 64 + lane] + rp[3072 + r * 64 + lane];
            #pragma unroll
            for (int off = 16; off >= 1; off >>= 1) v += __shfl_xor(v, off);
            if (l31 == 0)
                ls[wid * 32 + (r & 3) + 8 * (r >> 2) + 4 * h] = 1.0f / v;
        }
    }
    __syncthreads();
    // fused scale -> YQ2 frag-major, 2 tiles (2048 elems)
    #pragma unroll
    for (int p = 0; p < 8; ++p){
        int idx = (p << 8) + t;
        int tl = idx >> 10;               // 0 or 1
        int i1 = idx & 1023;
        int c = i1 >> 5, n = i1 & 31;
        size_t g = (size_t)(b * 32 + c) * HW + (nA + tl) * 32 + n;
        int j = n >> 4, hh = (n >> 3) & 1;
        YQ2[((size_t)b * 128 + nA + tl) * 1024 + j * 512 + (c + (hh << 5)) * 8 + (n & 7)]
            = f2bf(YQ[g] * ls[tl * 32 + n]);
    }
}

// ------- K7: MFMA value pass, 2 m-tiles/block (shared Q/Y stream) -------------
// grid 512: b = blk&7, mpair = blk>>3 (m-tiles 2p, 2p+1)
__global__ __launch_bounds__(256, 2) void k_attn_mfma(
    const unsigned short* __restrict__ Q1t, const unsigned short* __restrict__ K2t,
    const unsigned short* __restrict__ YKt, const unsigned short* __restrict__ YQ2,
    const float* __restrict__ M2, const float* __restrict__ c6w, const float* __restrict__ c6b,
    const float* __restrict__ x, float* __restrict__ xout)
{
    __shared__ float redA[4][16][64];
    __shared__ float redB[4][16][64];
    int t = threadIdx.x, wid = t >> 6, lane = t & 63;
    int l31 = lane & 31, h = lane >> 5;
    int b = blockIdx.x & 7, mpair = blockIdx.x >> 3;
    int mA = mpair * 2;
    size_t ktbA = ((size_t)b * 128 + mA) * 1024;

    bf16x8_t kbA0 = ldb(K2t + ktbA + lane * 8);
    bf16x8_t kbA1 = ldb(K2t + ktbA + 512 + lane * 8);
    bf16x8_t kbB0 = ldb(K2t + ktbA + 1024 + lane * 8);
    bf16x8_t kbB1 = ldb(K2t + ktbA + 1536 + lane * 8);

    f32x16_t oaccA, oaccB, zz;
    #pragma unroll
    for (int r = 0; r < 16; ++r){ oaccA[r] = 0.f; oaccB[r] = 0.f; zz[r] = 0.f; }

    const unsigned short* qp = Q1t + ((size_t)b * 128 + (wid << 5)) * 1024 + lane * 8;
    const unsigned short* yp = YQ2 + ((size_t)b * 128 + (wid << 5)) * 1024 + lane * 8;

    bf16x8_t a0 = ldb(qp), a1 = ldb(qp + 512);
    bf16x8_t y0 = ldb(yp), y1 = ldb(yp + 512);
    qp += 1024; yp += 1024;
    bf16x8_t a0n = ldb(qp), a1n = ldb(qp + 512);
    bf16x8_t y0n = ldb(yp), y1n = ldb(yp + 512);

    #pragma unroll 2
    for (int i = 0; i < 32; ++i){
        // two m-tile S chains from one shared (a,y) stream
        f32x16_t sA = mfma32(a0, kbA0, zz);
        sA = mfma32(a1, kbA1, sA);
        f32x16_t sB = mfma32(a0, kbB0, zz);
        sB = mfma32(a1, kbB1, sB);
        // prefetch tile i+2
        int adv = (i < 30) ? 1024 : 0;
        qp += adv; yp += adv;
        bf16x8_t a0nn = ldb(qp), a1nn = ldb(qp + 512);
        bf16x8_t y0nn = ldb(yp), y1nn = ldb(yp + 512);
        u32 P[8];
        #pragma unroll
        for (int tt = 0; tt < 8; ++tt)
            P[tt] = pkexp2(sA[2 * tt], sA[2 * tt + 1]);
        bf16x8_t e0, e1;
        cd2bfrag(P, e0, e1);
        __builtin_amdgcn_s_setprio(1);
        oaccA = mfma32(y0, e0, oaccA);
        oaccA = mfma32(y1, e1, oaccA);
        __builtin_amdgcn_s_setprio(0);
        #pragma unroll
        for (int tt = 0; tt < 8; ++tt)
            P[tt] = pkexp2(sB[2 * tt], sB[2 * tt + 1]);
        cd2bfrag(P, e0, e1);
        __builtin_amdgcn_s_setprio(1);
        oaccB = mfma32(y0, e0, oaccB);
        oaccB = mfma32(y1, e1, oaccB);
        __builtin_amdgcn_s_setprio(0);
        a0 = a0n; a1 = a1n; y0 = y0n; y1 = y1n;
        a0n = a0nn; a1n = a1nn; y0n = y0nn; y1n = y1nn;
    }
    #pragma unroll
    for (int r = 0; r < 16; ++r){
        redA[wid][r][lane] = oaccA[r];
        redB[wid][r][lane] = oaccB[r];
    }
    __syncthreads();
    if (wid >= 2) return;
    // wave 0 -> m-tile mA, wave 1 -> m-tile mA+1
    const float* rp = (wid == 0) ? &redA[0][0][0] : &redB[0][0][0];
    f32x16_t oacc;
    #pragma unroll
    for (int r = 0; r < 16; ++r)
        oacc[r] = rp[r * 64 + lane] + rp[1024 + r * 64 + lane]
                + rp[2048 + r * 64 + lane] + rp[3072 + r * 64 + lane];

    int mtile = mA + wid;
    int m0 = mtile * 32;
    size_t ktb = ((size_t)b * 128 + mtile) * 1024;

    u32 P[8];
    #pragma unroll
    for (int tt = 0; tt < 8; ++tt) P[tt] = pk2(oacc[2 * tt], oacc[2 * tt + 1]);
    bf16x8_t xb0, xb1;
    cd2bfrag(P, xb0, xb1);

    const float* w1p = c6w + l31 * 64;
    const float* m2p = M2 + b * 1024 + l31 * 32;
    int cb0 = 8 * h, cb1 = 16 + 8 * h;
    castu wa0, wa1, ma0, ma1;
    wa0.u = (u32x4_t){ pk2(w1p[cb0], w1p[cb0+1]), pk2(w1p[cb0+2], w1p[cb0+3]),
                       pk2(w1p[cb0+4], w1p[cb0+5]), pk2(w1p[cb0+6], w1p[cb0+7]) };
    wa1.u = (u32x4_t){ pk2(w1p[cb1], w1p[cb1+1]), pk2(w1p[cb1+2], w1p[cb1+3]),
                       pk2(w1p[cb1+4], w1p[cb1+5]), pk2(w1p[cb1+6], w1p[cb1+7]) };
    ma0.u = (u32x4_t){ pk2(m2p[cb0], m2p[cb0+1]), pk2(m2p[cb0+2], m2p[cb0+3]),
                       pk2(m2p[cb0+4], m2p[cb0+5]), pk2(m2p[cb0+6], m2p[cb0+7]) };
    ma1.u = (u32x4_t){ pk2(m2p[cb1], m2p[cb1+1]), pk2(m2p[cb1+2], m2p[cb1+3]),
                       pk2(m2p[cb1+4], m2p[cb1+5]), pk2(m2p[cb1+6], m2p[cb1+7]) };
    bf16x8_t ykb0 = ldb(YKt + ktb + lane * 8);
    bf16x8_t ykb1 = ldb(YKt + ktb + 512 + lane * 8);

    f32x16_t facc;
    #pragma unroll
    for (int r = 0; r < 16; ++r) facc[r] = c6b[(r & 3) + 8 * (r >> 2) + 4 * h];
    facc = mfma32(wa0.s, xb0, facc);
    facc = mfma32(wa1.s, xb1, facc);
    facc = mfma32(ma0.s, ykb0, facc);
    facc = mfma32(ma1.s, ykb1, facc);

    #pragma unroll
    for (int r = 0; r < 16; ++r){
        int o = (r & 3) + 8 * (r >> 2) + 4 * h;
        size_t gi = ((size_t)(b * 32 + o) << 12) + m0 + l31;
        xout[gi] = x[gi] + facc[r];
    }
}

// ---------------- K8: score conv + residual on y (LDS-staged) -----------------
__global__ __launch_bounds__(256) void k_score(
    const float* __restrict__ xout, const float* __restrict__ y,
    const float* __restrict__ sw, const float* __restrict__ sb,
    float* __restrict__ yout)
{
    __shared__ float xs[3][32][66];
    __shared__ float red[4][64];
    int tid = threadIdx.x;
    int b = blockIdx.x & 7, h = blockIdx.x >> 3;
    for (int i = 0; i < 24; ++i){
        int idx = i * 256 + tid;
        int w = idx & 63, ic = (idx >> 6) & 31, dr = idx >> 11;
        int hr = h + dr - 1;
        xs[dr][ic][1 + w] = (hr >= 0 && hr < 64) ? xout[((b * 32 + ic) << 12) + (hr << 6) + w] : 0.f;
    }
    if (tid < 96){ xs[tid >> 5][tid & 31][0] = 0.f; }
    else if (tid < 192){ int u = tid - 96; xs[u >> 5][u & 31][65] = 0.f; }
    __syncthreads();
    int w = tid & 63, icg = tid >> 6;
    float p = 0.f;
    #pragma unroll
    for (int i = 0; i < 8; ++i){
        int ic = icg * 8 + i;
        #pragma unroll
        for (int tap = 0; tap < 9; ++tap)
            p = fmaf(sw[ic * 9 + tap], xs[tap / 3][ic][w + tap % 3], p);
    }
    red[icg][w] = p;
    __syncthreads();
    if (tid < 64){
        int px = (h << 6) + tid;
        yout[b * HW + px] = y[b * HW + px] + sb[0]
                          + red[0][tid] + red[1][tid] + red[2][tid] + red[3][tid];
    }
}

extern "C" void kernel_launch(void* const* d_in, const int* in_sizes, int n_in,
                              void* d_out, int out_size, void* d_ws, size_t ws_size,
                              hipStream_t stream)
{
    (void)in_sizes; (void)n_in; (void)out_size; (void)ws_size;
    const float* x      = (const float*)d_in[0];
    const float* y      = (const float*)d_in[1];
    const float* conv_w = (const float*)d_in[2];
    const float* conv_b = (const float*)d_in[3];
    const float* score_w= (const float*)d_in[4];
    const float* score_b= (const float*)d_in[5];
    const float* c132_w = (const float*)d_in[6];
    const float* c132_b = (const float*)d_in[7];
    const float* q1w = (const float*)d_in[8];  const float* q1b = (const float*)d_in[9];
    const float* k1w = (const float*)d_in[10]; const float* k1b = (const float*)d_in[11];
    const float* q2w = (const float*)d_in[12]; const float* q2b = (const float*)d_in[13];
    const float* k2w = (const float*)d_in[14]; const float* k2b = (const float*)d_in[15];
    const float* q3w = (const float*)d_in[16]; const float* q3b = (const float*)d_in[17];
    const float* k3w = (const float*)d_in[18]; const float* k3b = (const float*)d_in[19];
    const float* c6w = (const float*)d_in[20]; const float* c6b = (const float*)d_in[21];

    float* ws = (float*)d_ws;
    const size_t SZ = 1048576;            // 8*32*4096
    float* Scp = ws;                      // 524288 f32
    float* M2  = ws + 524288;             // 8192 f32
    float* K1  = ws + 2 * SZ;             // 1M f32
    float* Q2  = ws + 3 * SZ;             // 1M f32
    float* YQf = ws + 4 * SZ;             // 1M f32
    unsigned short* Q1t = (unsigned short*)(ws + 5 * SZ);            // 1M bf16 (frag-major)
    unsigned short* K2t = (unsigned short*)(ws + 5 * SZ + SZ / 2);   // 1M bf16 (frag-major)
    unsigned short* YKt = (unsigned short*)(ws + 6 * SZ);            // 1M bf16 (frag-major)
    unsigned short* YQ2 = (unsigned short*)(ws + 6 * SZ + SZ / 2);   // 1M bf16 (frag-major)

    float* xout = (float*)d_out;
    float* yout = xout + SZ;

    k_front_mfma<<<dim3(32, 8), 256, 0, stream>>>(
        x, y, conv_w, conv_b, c132_w, c132_b,
        q1w, q1b, k1w, k1b, q2w, q2b, k2w, k2b, q3w, q3b, k3w, k3b,
        K1, Q2, YQf, Q1t, K2t, YKt);
    k_chan_part<<<512, 256, 0, stream>>>(K1, Q2, Scp);
    k_chan_fin<<<8, 1024, 0, stream>>>(Scp, c6w, M2);
    k_stats_mfma<<<512, 256, 0, stream>>>(Q1t, K2t, YQf, YQ2);
    k_attn_mfma<<<512, 256, 0, stream>>>(Q1t, K2t, YKt, YQ2, M2, c6w, c6b, x, xout);
    k_score<<<512, 256, 0, stream>>>(xout, y, score_w, score_b, yout);
}